// Round 19
// baseline (428.543 us; speedup 1.0000x reference)
//
#include <hip/hip_runtime.h>
#include <hip/hip_bf16.h>

#define NN 500000
#define TM 64   // 32 KB LDS x 4 blocks/CU (thread-capped) = 32 waves/CU

typedef __bf16 bf16x8 __attribute__((ext_vector_type(8)));
typedef float  fx4    __attribute__((ext_vector_type(4)));

// fragment-order address: element (o=row of W [outcol], k) -> per-wave MFMA
// fragment layout. oc = o>>4 selects (wave-col,c); step = kstep; lane=(ks,rl).
__device__ __forceinline__ int fragaddr(int o, int k, int nk) {
    int rl = o & 15, oc = o >> 4;
    int step = k >> 5, ks = (k >> 3) & 3, e = k & 7;
    return ((oc * nk + step) * 64 + (ks * 16 + rl)) * 8 + e;
}

// ---- prep_w: Wc = W2@W1 (fused, no ReLU between) -> fragment-ordered bf16;
//      mW1, mW2 likewise; bc = b2 + W2@b1 ----
__global__ __launch_bounds__(256) void prep_w(const float* __restrict__ W1,
    const float* __restrict__ W2, const float* __restrict__ mW1,
    const float* __restrict__ mW2, const float* __restrict__ b1,
    const float* __restrict__ b2, __bf16* __restrict__ Wp, float* __restrict__ bc) {
    __shared__ float w2row[128];
    int o = blockIdx.x, k = threadIdx.x;
    if (k < 128) w2row[k] = W2[o * 128 + k];
    __syncthreads();
    float acc = 0.f;
    for (int j = 0; j < 128; ++j) acc += w2row[j] * W1[j * 256 + k];
    Wp[fragaddr(o, k, 8)] = (__bf16)acc;                              // Wc [128][256]
    Wp[32768 + fragaddr(o, k, 8)] = (__bf16)mW1[o * 256 + k];         // mW1 [128][256]
    if (k < 128) Wp[65536 + fragaddr(o, k, 4)] = (__bf16)mW2[o * 128 + k]; // mW2 [128][128]
    if (k == 0) {
        float a = b2[o];
        for (int j = 0; j < 128; ++j) a += w2row[j] * b1[j];
        bc[o] = a;
    }
}

// per-wave GEMM, software-pipelined (depth-1 prefetch of A ds_reads and B
// global loads): A in LDS (swizzled, stride 512 B) rows wm*32+[0,32) x
// B (fragment-ordered bf16, L2) cols wc*32+[0,32) -> acc[2][2].
template<int NK>
__device__ __forceinline__ void gemm_block(const char* A, const __bf16* B,
                                           int lane, int wm, int wc, fx4 acc[2][2]) {
    const int rl = lane & 15, ks = lane >> 4;
    const __bf16* Bp = B + ((wc * 2 * NK) << 9) + (lane << 3);
    bf16x8 a[2], b[2];
    {
        const int kb = 16 * ks;
#pragma unroll
        for (int m = 0; m < 2; ++m) {
            int row = wm * 32 + m * 16 + rl;
            a[m] = *(const bf16x8*)(A + row * 512 + (kb ^ ((row & 7) << 4)));
        }
        b[0] = *(const bf16x8*)(Bp);
        b[1] = *(const bf16x8*)(Bp + (NK << 9));
    }
#pragma unroll
    for (int step = 0; step < NK; ++step) {
        bf16x8 an[2], bn[2];
        if (step + 1 < NK) {
            const int kb = 64 * (step + 1) + 16 * ks;
            bn[0] = *(const bf16x8*)(Bp + ((step + 1) << 9));
            bn[1] = *(const bf16x8*)(Bp + ((NK + step + 1) << 9));
#pragma unroll
            for (int m = 0; m < 2; ++m) {
                int row = wm * 32 + m * 16 + rl;
                an[m] = *(const bf16x8*)(A + row * 512 + (kb ^ ((row & 7) << 4)));
            }
        }
#pragma unroll
        for (int m = 0; m < 2; ++m)
#pragma unroll
            for (int c = 0; c < 2; ++c)
                acc[m][c] = __builtin_amdgcn_mfma_f32_16x16x32_bf16(a[m], b[c], acc[m][c], 0, 0, 0);
        if (step + 1 < NK) {
#pragma unroll
            for (int m = 0; m < 2; ++m) a[m] = an[m];
            b[0] = bn[0]; b[1] = bn[1];
        }
    }
}

// 512 threads = 8 waves tiling 2(row)x4(col) over the 64x128 tile.
// hrow (h[i]) loads deferred into P2's gemm window.
// L=0: f32 inputs, te inline, writes fte+h1 (bf16). L=1: bf16 in, f32 out.
template<int L>
__global__ __launch_bounds__(512, 4) void tgn_layer(
    const float* __restrict__ h32,  const float* __restrict__ feat,
    const float* __restrict__ ts,   const float* __restrict__ lu,
    const float* __restrict__ tw,   const float* __restrict__ tb,
    const __bf16* __restrict__ hsrc, __bf16* __restrict__ fte,
    const int* __restrict__ src,   const __bf16* __restrict__ Wp,
    const float* __restrict__ bc,  const float* __restrict__ mb1,
    const float* __restrict__ mb2, __bf16* __restrict__ hnext,
    float* __restrict__ out32)
{
    __shared__ __align__(16) char C[TM * 512];   // 32 KB, aliased per phase

    const int tid = threadIdx.x;
    const int r0  = blockIdx.x * TM;
    const int lane = tid & 63, wid = tid >> 6;
    const int wm = wid >> 2, wc = wid & 3;
    const int rl = lane & 15, ks = lane >> 4;
    const int rr = tid >> 4, cc = (tid & 15) * 8;

    int ii[2];
    // ---- P1: C = [ h[src] | feat+te ]; L0 writes fte ----
    if (L == 0) {
        int ss[2];
#pragma unroll
        for (int rb = 0; rb < 2; ++rb) {
            int i = r0 + rr + rb * 32; if (i >= NN) i = NN - 1;
            ii[rb] = i;
            ss[rb] = src[i];
        }
        fx4 g0[2], g1[2], f0[2], f1[2];
        float dts[2];
#pragma unroll
        for (int rb = 0; rb < 2; ++rb) {
            const fx4* gp = (const fx4*)(h32 + (size_t)ss[rb] * 128 + cc);
            g0[rb] = gp[0]; g1[rb] = gp[1];
            const fx4* fp = (const fx4*)(feat + (size_t)ii[rb] * 128 + cc);
            f0[rb] = __builtin_nontemporal_load(fp);       // read-once stream
            f1[rb] = __builtin_nontemporal_load(fp + 1);
            dts[rb] = ts[ii[rb]] - lu[ss[rb]];
        }
        const fx4 tw0 = *(const fx4*)(tw + cc), tw1 = *(const fx4*)(tw + cc + 4);
        const fx4 tb0 = *(const fx4*)(tb + cc), tb1 = *(const fx4*)(tb + cc + 4);
        const float i2p = 0.15915494309189535f;
#pragma unroll
        for (int rb = 0; rb < 2; ++rb) {
            int r = rr + rb * 32;
            bf16x8 hv, fv;
#pragma unroll
            for (int j = 0; j < 4; ++j) {
                hv[j]     = (__bf16)g0[rb][j];
                hv[4 + j] = (__bf16)g1[rb][j];
                float a0 = (dts[rb] * tw0[j] + tb0[j]) * i2p;
                float a1 = (dts[rb] * tw1[j] + tb1[j]) * i2p;
                fv[j]     = (__bf16)(f0[rb][j] + __builtin_amdgcn_cosf(__builtin_amdgcn_fractf(a0)));
                fv[4 + j] = (__bf16)(f1[rb][j] + __builtin_amdgcn_cosf(__builtin_amdgcn_fractf(a1)));
            }
            *(bf16x8*)(fte + (size_t)ii[rb] * 128 + cc) = fv;   // reuse in L1
            int swz = (r & 7) << 4;
            *(bf16x8*)(C + r * 512 + ((2 * cc) ^ swz))       = hv;
            *(bf16x8*)(C + r * 512 + ((256 + 2 * cc) ^ swz)) = fv;
        }
    } else {
        bf16x8 hv[2], fv[2];
#pragma unroll
        for (int rb = 0; rb < 2; ++rb) {
            int i = r0 + rr + rb * 32; if (i >= NN) i = NN - 1;
            ii[rb] = i;
            int s = src[i];
            hv[rb] = *(const bf16x8*)(hsrc + (size_t)s * 128 + cc);
            fv[rb] = *(const bf16x8*)(fte + (size_t)i * 128 + cc);
        }
#pragma unroll
        for (int rb = 0; rb < 2; ++rb) {
            int r = rr + rb * 32;
            int swz = (r & 7) << 4;
            *(bf16x8*)(C + r * 512 + ((2 * cc) ^ swz))       = hv[rb];
            *(bf16x8*)(C + r * 512 + ((256 + 2 * cc) ^ swz)) = fv[rb];
        }
    }
    __syncthreads();

    // ---- P2: hb = relu(C @ Wc^T + bc); C := [ h[i] | hb ] ----
    {
        fx4 acc[2][2] = {};
        gemm_block<8>(C, Wp, lane, wm, wc, acc);
        // hrow loads deferred here: issued after gemm, consumed after barrier
        bf16x8 hrow[2];
        if (L == 0) {
#pragma unroll
            for (int rb = 0; rb < 2; ++rb) {
                const fx4* qp = (const fx4*)(h32 + (size_t)ii[rb] * 128 + cc);
                fx4 q0 = qp[0], q1 = qp[1];
#pragma unroll
                for (int j = 0; j < 4; ++j) { hrow[rb][j] = (__bf16)q0[j]; hrow[rb][4 + j] = (__bf16)q1[j]; }
            }
        } else {
#pragma unroll
            for (int rb = 0; rb < 2; ++rb)
                hrow[rb] = *(const bf16x8*)(hsrc + (size_t)ii[rb] * 128 + cc);
        }
        float bb0 = bc[wc * 32 + rl], bb1 = bc[wc * 32 + 16 + rl];
        __syncthreads();     // all reads of C done
#pragma unroll
        for (int m = 0; m < 2; ++m)
#pragma unroll
            for (int c = 0; c < 2; ++c) {
                int col = wc * 32 + c * 16 + rl;
                float bb = c ? bb1 : bb0;
#pragma unroll
                for (int g = 0; g < 4; ++g) {
                    int row = wm * 32 + m * 16 + ks * 4 + g;
                    float v = fmaxf(acc[m][c][g] + bb, 0.0f);
                    *(__bf16*)(C + row * 512 + ((256 + 2 * col) ^ ((row & 7) << 4))) = (__bf16)v;
                }
            }
#pragma unroll
        for (int rb = 0; rb < 2; ++rb) {
            int r = rr + rb * 32;
            *(bf16x8*)(C + r * 512 + ((2 * cc) ^ ((r & 7) << 4))) = hrow[rb];
        }
    }
    __syncthreads();

    // ---- P3: m1 = relu(x @ mW1^T + mb1) -> C first half ----
    {
        fx4 acc[2][2] = {};
        gemm_block<8>(C, Wp + 32768, lane, wm, wc, acc);
        float bb0 = mb1[wc * 32 + rl], bb1 = mb1[wc * 32 + 16 + rl];
        __syncthreads();
#pragma unroll
        for (int m = 0; m < 2; ++m)
#pragma unroll
            for (int c = 0; c < 2; ++c) {
                int col = wc * 32 + c * 16 + rl;
                float bb = c ? bb1 : bb0;
#pragma unroll
                for (int g = 0; g < 4; ++g) {
                    int row = wm * 32 + m * 16 + ks * 4 + g;
                    float v = fmaxf(acc[m][c][g] + bb, 0.0f);
                    *(__bf16*)(C + row * 512 + ((2 * col) ^ ((row & 7) << 4))) = (__bf16)v;
                }
            }
    }
    __syncthreads();

    // ---- P4: out = m1 @ mW2^T + mb2 (K=128), repack via LDS, store ----
    {
        fx4 acc[2][2] = {};
        gemm_block<4>(C, Wp + 65536, lane, wm, wc, acc);
        float bb0 = mb2[wc * 32 + rl], bb1 = mb2[wc * 32 + 16 + rl];
        __syncthreads();
        if (L == 0) {
#pragma unroll
            for (int m = 0; m < 2; ++m)
#pragma unroll
                for (int c = 0; c < 2; ++c) {
                    int col = wc * 32 + c * 16 + rl;
                    float bb = c ? bb1 : bb0;
#pragma unroll
                    for (int g = 0; g < 4; ++g) {
                        int row = wm * 32 + m * 16 + ks * 4 + g;
                        *(__bf16*)(C + row * 256 + 2 * col) = (__bf16)(acc[m][c][g] + bb);
                    }
                }
            __syncthreads();
#pragma unroll
            for (int it = 0; it < 2; ++it) {
                int r = rr + 32 * it;
                int i = r0 + r;
                if (i < NN)
                    *(bf16x8*)((char*)hnext + (size_t)i * 256 + (tid & 15) * 16) =
                        *(const bf16x8*)(C + r * 256 + (tid & 15) * 16);
            }
        } else {
#pragma unroll
            for (int m = 0; m < 2; ++m)
#pragma unroll
                for (int c = 0; c < 2; ++c) {
                    int col = wc * 32 + c * 16 + rl;
                    float bb = c ? bb1 : bb0;
#pragma unroll
                    for (int g = 0; g < 4; ++g) {
                        int row = wm * 32 + m * 16 + ks * 4 + g;
                        *(float*)(C + row * 512 + 4 * col) = acc[m][c][g] + bb;
                    }
                }
            __syncthreads();
#pragma unroll
            for (int it = 0; it < 4; ++it) {
                int r = (tid >> 5) + 16 * it;
                int i = r0 + r;
                if (i < NN) {
                    fx4 v = *(const fx4*)(C + r * 512 + (tid & 31) * 16);
                    __builtin_nontemporal_store(v,
                        (fx4*)((char*)out32 + (size_t)i * 512 + (tid & 31) * 16));
                }
            }
        }
    }
}

extern "C" void kernel_launch(void* const* d_in, const int* in_sizes, int n_in,
                              void* d_out, int out_size, void* d_ws, size_t ws_size,
                              hipStream_t stream) {
    const float* h    = (const float*)d_in[0];
    const float* feat = (const float*)d_in[1];
    const float* ts   = (const float*)d_in[2];
    const float* lu   = (const float*)d_in[3];
    const float* tw   = (const float*)d_in[4];
    const float* tb   = (const float*)d_in[5];
    const float* W1   = (const float*)d_in[6];
    const float* b1   = (const float*)d_in[7];
    const float* W2   = (const float*)d_in[8];
    const float* b2   = (const float*)d_in[9];
    const float* mW1  = (const float*)d_in[10];
    const float* mb1  = (const float*)d_in[11];
    const float* mW2  = (const float*)d_in[12];
    const float* mb2  = (const float*)d_in[13];
    const int*   src  = (const int*)d_in[14];

    char* ws = (char*)d_ws;
    __bf16* Wp  = (__bf16*)ws;                        // 163840 B
    float*  bcb = (float*)(ws + 163840);              // 512 B
    __bf16* fte = (__bf16*)(ws + 196608);             // 128 MB
    __bf16* h1  = (__bf16*)(ws + 196608 + 128000000); // 128 MB
    float*  out = (float*)d_out;

    prep_w<<<dim3(128), dim3(256), 0, stream>>>(W1, W2, mW1, mW2, b1, b2, Wp, bcb);
    int grid = (NN + TM - 1) / TM;   // 7813
    tgn_layer<0><<<dim3(grid), dim3(512), 0, stream>>>(h, feat, ts, lu, tw, tb,
        nullptr, fte, src, Wp, bcb, mb1, mb2, h1, nullptr);
    tgn_layer<1><<<dim3(grid), dim3(512), 0, stream>>>(nullptr, nullptr, nullptr,
        nullptr, nullptr, nullptr, h1, fte, src, Wp, bcb, mb1, mb2, nullptr, out);
}

// Round 20
// 370.338 us; speedup vs baseline: 1.1572x; 1.1572x over previous
//
#include <hip/hip_runtime.h>
#include <hip/hip_bf16.h>

#define NN 500000
#define TM 96   // 48 KB LDS -> 3 blocks/CU: best measured (R18, 378 us)

typedef __bf16 bf16x8 __attribute__((ext_vector_type(8)));
typedef float  fx4    __attribute__((ext_vector_type(4)));

// fragment-order address: element (o=row of W [outcol], k) -> per-wave MFMA
// fragment layout. oc = o>>4 selects (wave-col,c); step = kstep; lane=(ks,rl).
__device__ __forceinline__ int fragaddr(int o, int k, int nk) {
    int rl = o & 15, oc = o >> 4;
    int step = k >> 5, ks = (k >> 3) & 3, e = k & 7;
    return ((oc * nk + step) * 64 + (ks * 16 + rl)) * 8 + e;
}

// ---- prep_w: Wc = W2@W1 (fused, no ReLU between) -> fragment-ordered bf16;
//      mW1, mW2 likewise; bc = b2 + W2@b1 ----
__global__ __launch_bounds__(256) void prep_w(const float* __restrict__ W1,
    const float* __restrict__ W2, const float* __restrict__ mW1,
    const float* __restrict__ mW2, const float* __restrict__ b1,
    const float* __restrict__ b2, __bf16* __restrict__ Wp, float* __restrict__ bc) {
    __shared__ float w2row[128];
    int o = blockIdx.x, k = threadIdx.x;
    if (k < 128) w2row[k] = W2[o * 128 + k];
    __syncthreads();
    float acc = 0.f;
    for (int j = 0; j < 128; ++j) acc += w2row[j] * W1[j * 256 + k];
    Wp[fragaddr(o, k, 8)] = (__bf16)acc;                              // Wc [128][256]
    Wp[32768 + fragaddr(o, k, 8)] = (__bf16)mW1[o * 256 + k];         // mW1 [128][256]
    if (k < 128) Wp[65536 + fragaddr(o, k, 4)] = (__bf16)mW2[o * 128 + k]; // mW2 [128][128]
    if (k == 0) {
        float a = b2[o];
        for (int j = 0; j < 128; ++j) a += w2row[j] * b1[j];
        bc[o] = a;
    }
}

// per-wave GEMM, software-pipelined (depth-1 prefetch of A ds_reads and B
// global loads): A in LDS (swizzled, stride 512 B) rows wm*48+[0,48) x
// B (fragment-ordered bf16, L2) cols wc*32+[0,32) -> acc[3][2].
template<int NK>
__device__ __forceinline__ void gemm_block(const char* A, const __bf16* B,
                                           int lane, int wm, int wc, fx4 acc[3][2]) {
    const int rl = lane & 15, ks = lane >> 4;
    const __bf16* Bp = B + ((wc * 2 * NK) << 9) + (lane << 3);
    bf16x8 a[3], b[2];
    {
        const int kb = 16 * ks;
#pragma unroll
        for (int m = 0; m < 3; ++m) {
            int row = wm * 48 + m * 16 + rl;
            a[m] = *(const bf16x8*)(A + row * 512 + (kb ^ ((row & 7) << 4)));
        }
        b[0] = *(const bf16x8*)(Bp);
        b[1] = *(const bf16x8*)(Bp + (NK << 9));
    }
#pragma unroll
    for (int step = 0; step < NK; ++step) {
        bf16x8 an[3], bn[2];
        if (step + 1 < NK) {
            const int kb = 64 * (step + 1) + 16 * ks;
            bn[0] = *(const bf16x8*)(Bp + ((step + 1) << 9));
            bn[1] = *(const bf16x8*)(Bp + ((NK + step + 1) << 9));
#pragma unroll
            for (int m = 0; m < 3; ++m) {
                int row = wm * 48 + m * 16 + rl;
                an[m] = *(const bf16x8*)(A + row * 512 + (kb ^ ((row & 7) << 4)));
            }
        }
#pragma unroll
        for (int m = 0; m < 3; ++m)
#pragma unroll
            for (int c = 0; c < 2; ++c)
                acc[m][c] = __builtin_amdgcn_mfma_f32_16x16x32_bf16(a[m], b[c], acc[m][c], 0, 0, 0);
        if (step + 1 < NK) {
#pragma unroll
            for (int m = 0; m < 3; ++m) a[m] = an[m];
            b[0] = bn[0]; b[1] = bn[1];
        }
    }
}

// 512 threads = 8 waves tiling 2(row)x4(col) over the 96x128 tile.
// hrow (h[i]) loads deferred into P2's gemm window.
// L=0: f32 inputs, te inline, writes fte+h1 (bf16). L=1: bf16 in, f32 out.
// NT hints: read-once streams (feat in L0, fte in L1) skip L3 to preserve
// the gather table's (h / h1) residency.
template<int L>
__global__ __launch_bounds__(512, 4) void tgn_layer(
    const float* __restrict__ h32,  const float* __restrict__ feat,
    const float* __restrict__ ts,   const float* __restrict__ lu,
    const float* __restrict__ tw,   const float* __restrict__ tb,
    const __bf16* __restrict__ hsrc, __bf16* __restrict__ fte,
    const int* __restrict__ src,   const __bf16* __restrict__ Wp,
    const float* __restrict__ bc,  const float* __restrict__ mb1,
    const float* __restrict__ mb2, __bf16* __restrict__ hnext,
    float* __restrict__ out32)
{
    __shared__ __align__(16) char C[TM * 512];   // 48 KB, aliased per phase

    const int tid = threadIdx.x;
    const int r0  = blockIdx.x * TM;
    const int lane = tid & 63, wid = tid >> 6;
    const int wm = wid >> 2, wc = wid & 3;
    const int rl = lane & 15, ks = lane >> 4;
    const int rr = tid >> 4, cc = (tid & 15) * 8;

    int ii[3];
    // ---- P1: C = [ h[src] | feat+te ]; L0 writes fte ----
    if (L == 0) {
        int ss[3];
#pragma unroll
        for (int rb = 0; rb < 3; ++rb) {
            int i = r0 + rr + rb * 32; if (i >= NN) i = NN - 1;
            ii[rb] = i;
            ss[rb] = src[i];
        }
        fx4 g0[3], g1[3], f0[3], f1[3];
        float dts[3];
#pragma unroll
        for (int rb = 0; rb < 3; ++rb) {
            const fx4* gp = (const fx4*)(h32 + (size_t)ss[rb] * 128 + cc);
            g0[rb] = gp[0]; g1[rb] = gp[1];
            const fx4* fp = (const fx4*)(feat + (size_t)ii[rb] * 128 + cc);
            f0[rb] = __builtin_nontemporal_load(fp);       // read-once stream
            f1[rb] = __builtin_nontemporal_load(fp + 1);
            dts[rb] = ts[ii[rb]] - lu[ss[rb]];
        }
        const fx4 tw0 = *(const fx4*)(tw + cc), tw1 = *(const fx4*)(tw + cc + 4);
        const fx4 tb0 = *(const fx4*)(tb + cc), tb1 = *(const fx4*)(tb + cc + 4);
        const float i2p = 0.15915494309189535f;
#pragma unroll
        for (int rb = 0; rb < 3; ++rb) {
            int r = rr + rb * 32;
            bf16x8 hv, fv;
#pragma unroll
            for (int j = 0; j < 4; ++j) {
                hv[j]     = (__bf16)g0[rb][j];
                hv[4 + j] = (__bf16)g1[rb][j];
                float a0 = (dts[rb] * tw0[j] + tb0[j]) * i2p;
                float a1 = (dts[rb] * tw1[j] + tb1[j]) * i2p;
                fv[j]     = (__bf16)(f0[rb][j] + __builtin_amdgcn_cosf(__builtin_amdgcn_fractf(a0)));
                fv[4 + j] = (__bf16)(f1[rb][j] + __builtin_amdgcn_cosf(__builtin_amdgcn_fractf(a1)));
            }
            *(bf16x8*)(fte + (size_t)ii[rb] * 128 + cc) = fv;   // reuse in L1
            int swz = (r & 7) << 4;
            *(bf16x8*)(C + r * 512 + ((2 * cc) ^ swz))       = hv;
            *(bf16x8*)(C + r * 512 + ((256 + 2 * cc) ^ swz)) = fv;
        }
    } else {
        bf16x8 hv[3], fv[3];
#pragma unroll
        for (int rb = 0; rb < 3; ++rb) {
            int i = r0 + rr + rb * 32; if (i >= NN) i = NN - 1;
            ii[rb] = i;
            int s = src[i];
            hv[rb] = *(const bf16x8*)(hsrc + (size_t)s * 128 + cc);
            fv[rb] = __builtin_nontemporal_load(
                         (const bf16x8*)(fte + (size_t)i * 128 + cc));  // read-once
        }
#pragma unroll
        for (int rb = 0; rb < 3; ++rb) {
            int r = rr + rb * 32;
            int swz = (r & 7) << 4;
            *(bf16x8*)(C + r * 512 + ((2 * cc) ^ swz))       = hv[rb];
            *(bf16x8*)(C + r * 512 + ((256 + 2 * cc) ^ swz)) = fv[rb];
        }
    }
    __syncthreads();

    // ---- P2: hb = relu(C @ Wc^T + bc); C := [ h[i] | hb ] ----
    {
        fx4 acc[3][2] = {};
        gemm_block<8>(C, Wp, lane, wm, wc, acc);
        // hrow loads deferred here: issued after gemm, consumed after barrier
        bf16x8 hrow[3];
        if (L == 0) {
#pragma unroll
            for (int rb = 0; rb < 3; ++rb) {
                const fx4* qp = (const fx4*)(h32 + (size_t)ii[rb] * 128 + cc);
                fx4 q0 = qp[0], q1 = qp[1];
#pragma unroll
                for (int j = 0; j < 4; ++j) { hrow[rb][j] = (__bf16)q0[j]; hrow[rb][4 + j] = (__bf16)q1[j]; }
            }
        } else {
#pragma unroll
            for (int rb = 0; rb < 3; ++rb)
                hrow[rb] = *(const bf16x8*)(hsrc + (size_t)ii[rb] * 128 + cc);
        }
        float bb0 = bc[wc * 32 + rl], bb1 = bc[wc * 32 + 16 + rl];
        __syncthreads();     // all reads of C done
#pragma unroll
        for (int m = 0; m < 3; ++m)
#pragma unroll
            for (int c = 0; c < 2; ++c) {
                int col = wc * 32 + c * 16 + rl;
                float bb = c ? bb1 : bb0;
#pragma unroll
                for (int g = 0; g < 4; ++g) {
                    int row = wm * 48 + m * 16 + ks * 4 + g;
                    float v = fmaxf(acc[m][c][g] + bb, 0.0f);
                    *(__bf16*)(C + row * 512 + ((256 + 2 * col) ^ ((row & 7) << 4))) = (__bf16)v;
                }
            }
#pragma unroll
        for (int rb = 0; rb < 3; ++rb) {
            int r = rr + rb * 32;
            *(bf16x8*)(C + r * 512 + ((2 * cc) ^ ((r & 7) << 4))) = hrow[rb];
        }
    }
    __syncthreads();

    // ---- P3: m1 = relu(x @ mW1^T + mb1) -> C first half ----
    {
        fx4 acc[3][2] = {};
        gemm_block<8>(C, Wp + 32768, lane, wm, wc, acc);
        float bb0 = mb1[wc * 32 + rl], bb1 = mb1[wc * 32 + 16 + rl];
        __syncthreads();
#pragma unroll
        for (int m = 0; m < 3; ++m)
#pragma unroll
            for (int c = 0; c < 2; ++c) {
                int col = wc * 32 + c * 16 + rl;
                float bb = c ? bb1 : bb0;
#pragma unroll
                for (int g = 0; g < 4; ++g) {
                    int row = wm * 48 + m * 16 + ks * 4 + g;
                    float v = fmaxf(acc[m][c][g] + bb, 0.0f);
                    *(__bf16*)(C + row * 512 + ((2 * col) ^ ((row & 7) << 4))) = (__bf16)v;
                }
            }
    }
    __syncthreads();

    // ---- P4: out = m1 @ mW2^T + mb2 (K=128), repack via LDS, store ----
    {
        fx4 acc[3][2] = {};
        gemm_block<4>(C, Wp + 65536, lane, wm, wc, acc);
        float bb0 = mb2[wc * 32 + rl], bb1 = mb2[wc * 32 + 16 + rl];
        __syncthreads();
        if (L == 0) {
#pragma unroll
            for (int m = 0; m < 3; ++m)
#pragma unroll
                for (int c = 0; c < 2; ++c) {
                    int col = wc * 32 + c * 16 + rl;
                    float bb = c ? bb1 : bb0;
#pragma unroll
                    for (int g = 0; g < 4; ++g) {
                        int row = wm * 48 + m * 16 + ks * 4 + g;
                        *(__bf16*)(C + row * 256 + 2 * col) = (__bf16)(acc[m][c][g] + bb);
                    }
                }
            __syncthreads();
#pragma unroll
            for (int it = 0; it < 3; ++it) {
                int r = rr + 32 * it;
                int i = r0 + r;
                if (i < NN)
                    *(bf16x8*)((char*)hnext + (size_t)i * 256 + (tid & 15) * 16) =
                        *(const bf16x8*)(C + r * 256 + (tid & 15) * 16);
            }
        } else {
#pragma unroll
            for (int m = 0; m < 3; ++m)
#pragma unroll
                for (int c = 0; c < 2; ++c) {
                    int col = wc * 32 + c * 16 + rl;
                    float bb = c ? bb1 : bb0;
#pragma unroll
                    for (int g = 0; g < 4; ++g) {
                        int row = wm * 48 + m * 16 + ks * 4 + g;
                        *(float*)(C + row * 512 + 4 * col) = acc[m][c][g] + bb;
                    }
                }
            __syncthreads();
#pragma unroll
            for (int it = 0; it < 6; ++it) {
                int r = (tid >> 5) + 16 * it;
                int i = r0 + r;
                if (i < NN) {
                    fx4 v = *(const fx4*)(C + r * 512 + (tid & 31) * 16);
                    __builtin_nontemporal_store(v,
                        (fx4*)((char*)out32 + (size_t)i * 512 + (tid & 31) * 16));
                }
            }
        }
    }
}

extern "C" void kernel_launch(void* const* d_in, const int* in_sizes, int n_in,
                              void* d_out, int out_size, void* d_ws, size_t ws_size,
                              hipStream_t stream) {
    const float* h    = (const float*)d_in[0];
    const float* feat = (const float*)d_in[1];
    const float* ts   = (const float*)d_in[2];
    const float* lu   = (const float*)d_in[3];
    const float* tw   = (const float*)d_in[4];
    const float* tb   = (const float*)d_in[5];
    const float* W1   = (const float*)d_in[6];
    const float* b1   = (const float*)d_in[7];
    const float* W2   = (const float*)d_in[8];
    const float* b2   = (const float*)d_in[9];
    const float* mW1  = (const float*)d_in[10];
    const float* mb1  = (const float*)d_in[11];
    const float* mW2  = (const float*)d_in[12];
    const float* mb2  = (const float*)d_in[13];
    const int*   src  = (const int*)d_in[14];

    char* ws = (char*)d_ws;
    __bf16* Wp  = (__bf16*)ws;                        // 163840 B
    float*  bcb = (float*)(ws + 163840);              // 512 B
    __bf16* fte = (__bf16*)(ws + 196608);             // 128 MB
    __bf16* h1  = (__bf16*)(ws + 196608 + 128000000); // 128 MB
    float*  out = (float*)d_out;

    prep_w<<<dim3(128), dim3(256), 0, stream>>>(W1, W2, mW1, mW2, b1, b2, Wp, bcb);
    int grid = (NN + TM - 1) / TM;   // 5209
    tgn_layer<0><<<dim3(grid), dim3(512), 0, stream>>>(h, feat, ts, lu, tw, tb,
        nullptr, fte, src, Wp, bcb, mb1, mb2, h1, nullptr);
    tgn_layer<1><<<dim3(grid), dim3(512), 0, stream>>>(nullptr, nullptr, nullptr,
        nullptr, nullptr, nullptr, h1, fte, src, Wp, bcb, mb1, mb2, nullptr, out);
}

// Round 21
// 368.686 us; speedup vs baseline: 1.1624x; 1.0045x over previous
//
#include <hip/hip_runtime.h>
#include <hip/hip_bf16.h>

#define NN 500000
#define TM 96   // 48 KB LDS -> 3 blocks/CU: best measured (R18/R20)

typedef __bf16 bf16x8 __attribute__((ext_vector_type(8)));
typedef float  fx4    __attribute__((ext_vector_type(4)));

// fragment-order address: element (o=row of W [outcol], k) -> per-wave MFMA
// fragment layout. oc = o>>4 selects (wave-col,c); step = kstep; lane=(ks,rl).
__device__ __forceinline__ int fragaddr(int o, int k, int nk) {
    int rl = o & 15, oc = o >> 4;
    int step = k >> 5, ks = (k >> 3) & 3, e = k & 7;
    return ((oc * nk + step) * 64 + (ks * 16 + rl)) * 8 + e;
}

// ---- prep_w: Wc = W2@W1 (fused, no ReLU between) -> fragment-ordered bf16;
//      mW1, mW2 likewise; bc = b2 + W2@b1 ----
__global__ __launch_bounds__(256) void prep_w(const float* __restrict__ W1,
    const float* __restrict__ W2, const float* __restrict__ mW1,
    const float* __restrict__ mW2, const float* __restrict__ b1,
    const float* __restrict__ b2, __bf16* __restrict__ Wp, float* __restrict__ bc) {
    __shared__ float w2row[128];
    int o = blockIdx.x, k = threadIdx.x;
    if (k < 128) w2row[k] = W2[o * 128 + k];
    __syncthreads();
    float acc = 0.f;
    for (int j = 0; j < 128; ++j) acc += w2row[j] * W1[j * 256 + k];
    Wp[fragaddr(o, k, 8)] = (__bf16)acc;                              // Wc [128][256]
    Wp[32768 + fragaddr(o, k, 8)] = (__bf16)mW1[o * 256 + k];         // mW1 [128][256]
    if (k < 128) Wp[65536 + fragaddr(o, k, 4)] = (__bf16)mW2[o * 128 + k]; // mW2 [128][128]
    if (k == 0) {
        float a = b2[o];
        for (int j = 0; j < 128; ++j) a += w2row[j] * b1[j];
        bc[o] = a;
    }
}

// per-wave GEMM, software-pipelined (depth-1 prefetch of A ds_reads and B
// global loads): A in LDS (swizzled, stride 512 B) rows wm*48+[0,48) x
// B (fragment-ordered bf16, L2) cols wc*32+[0,32) -> acc[3][2].
template<int NK>
__device__ __forceinline__ void gemm_block(const char* A, const __bf16* B,
                                           int lane, int wm, int wc, fx4 acc[3][2]) {
    const int rl = lane & 15, ks = lane >> 4;
    const __bf16* Bp = B + ((wc * 2 * NK) << 9) + (lane << 3);
    bf16x8 a[3], b[2];
    {
        const int kb = 16 * ks;
#pragma unroll
        for (int m = 0; m < 3; ++m) {
            int row = wm * 48 + m * 16 + rl;
            a[m] = *(const bf16x8*)(A + row * 512 + (kb ^ ((row & 7) << 4)));
        }
        b[0] = *(const bf16x8*)(Bp);
        b[1] = *(const bf16x8*)(Bp + (NK << 9));
    }
#pragma unroll
    for (int step = 0; step < NK; ++step) {
        bf16x8 an[3], bn[2];
        if (step + 1 < NK) {
            const int kb = 64 * (step + 1) + 16 * ks;
            bn[0] = *(const bf16x8*)(Bp + ((step + 1) << 9));
            bn[1] = *(const bf16x8*)(Bp + ((NK + step + 1) << 9));
#pragma unroll
            for (int m = 0; m < 3; ++m) {
                int row = wm * 48 + m * 16 + rl;
                an[m] = *(const bf16x8*)(A + row * 512 + (kb ^ ((row & 7) << 4)));
            }
        }
#pragma unroll
        for (int m = 0; m < 3; ++m)
#pragma unroll
            for (int c = 0; c < 2; ++c)
                acc[m][c] = __builtin_amdgcn_mfma_f32_16x16x32_bf16(a[m], b[c], acc[m][c], 0, 0, 0);
        if (step + 1 < NK) {
#pragma unroll
            for (int m = 0; m < 3; ++m) a[m] = an[m];
            b[0] = bn[0]; b[1] = bn[1];
        }
    }
}

// 512 threads = 8 waves tiling 2(row)x4(col) over the 96x128 tile.
// hrow (h[i]) loads deferred into P2's gemm window.
// L=0: f32 inputs, te inline, writes fte+h1 (bf16, NT). L=1: bf16 in, f32 out (NT).
// L3 steering: all read-once streams (feat, fte-in-L1) and write-once streams
// (fte/h1 in L0, out in L1) are nontemporal, preserving the gather table's
// (h / h1) L3 residency.
template<int L>
__global__ __launch_bounds__(512, 4) void tgn_layer(
    const float* __restrict__ h32,  const float* __restrict__ feat,
    const float* __restrict__ ts,   const float* __restrict__ lu,
    const float* __restrict__ tw,   const float* __restrict__ tb,
    const __bf16* __restrict__ hsrc, __bf16* __restrict__ fte,
    const int* __restrict__ src,   const __bf16* __restrict__ Wp,
    const float* __restrict__ bc,  const float* __restrict__ mb1,
    const float* __restrict__ mb2, __bf16* __restrict__ hnext,
    float* __restrict__ out32)
{
    __shared__ __align__(16) char C[TM * 512];   // 48 KB, aliased per phase

    const int tid = threadIdx.x;
    const int r0  = blockIdx.x * TM;
    const int lane = tid & 63, wid = tid >> 6;
    const int wm = wid >> 2, wc = wid & 3;
    const int rl = lane & 15, ks = lane >> 4;
    const int rr = tid >> 4, cc = (tid & 15) * 8;

    int ii[3];
    // ---- P1: C = [ h[src] | feat+te ]; L0 writes fte (NT) ----
    if (L == 0) {
        int ss[3];
#pragma unroll
        for (int rb = 0; rb < 3; ++rb) {
            int i = r0 + rr + rb * 32; if (i >= NN) i = NN - 1;
            ii[rb] = i;
            ss[rb] = src[i];
        }
        fx4 g0[3], g1[3], f0[3], f1[3];
        float dts[3];
#pragma unroll
        for (int rb = 0; rb < 3; ++rb) {
            const fx4* gp = (const fx4*)(h32 + (size_t)ss[rb] * 128 + cc);
            g0[rb] = gp[0]; g1[rb] = gp[1];
            const fx4* fp = (const fx4*)(feat + (size_t)ii[rb] * 128 + cc);
            f0[rb] = __builtin_nontemporal_load(fp);       // read-once stream
            f1[rb] = __builtin_nontemporal_load(fp + 1);
            dts[rb] = ts[ii[rb]] - lu[ss[rb]];
        }
        const fx4 tw0 = *(const fx4*)(tw + cc), tw1 = *(const fx4*)(tw + cc + 4);
        const fx4 tb0 = *(const fx4*)(tb + cc), tb1 = *(const fx4*)(tb + cc + 4);
        const float i2p = 0.15915494309189535f;
#pragma unroll
        for (int rb = 0; rb < 3; ++rb) {
            int r = rr + rb * 32;
            bf16x8 hv, fv;
#pragma unroll
            for (int j = 0; j < 4; ++j) {
                hv[j]     = (__bf16)g0[rb][j];
                hv[4 + j] = (__bf16)g1[rb][j];
                float a0 = (dts[rb] * tw0[j] + tb0[j]) * i2p;
                float a1 = (dts[rb] * tw1[j] + tb1[j]) * i2p;
                fv[j]     = (__bf16)(f0[rb][j] + __builtin_amdgcn_cosf(__builtin_amdgcn_fractf(a0)));
                fv[4 + j] = (__bf16)(f1[rb][j] + __builtin_amdgcn_cosf(__builtin_amdgcn_fractf(a1)));
            }
            __builtin_nontemporal_store(fv,
                (bf16x8*)(fte + (size_t)ii[rb] * 128 + cc));   // write-once stream
            int swz = (r & 7) << 4;
            *(bf16x8*)(C + r * 512 + ((2 * cc) ^ swz))       = hv;
            *(bf16x8*)(C + r * 512 + ((256 + 2 * cc) ^ swz)) = fv;
        }
    } else {
        bf16x8 hv[3], fv[3];
#pragma unroll
        for (int rb = 0; rb < 3; ++rb) {
            int i = r0 + rr + rb * 32; if (i >= NN) i = NN - 1;
            ii[rb] = i;
            int s = src[i];
            hv[rb] = *(const bf16x8*)(hsrc + (size_t)s * 128 + cc);
            fv[rb] = __builtin_nontemporal_load(
                         (const bf16x8*)(fte + (size_t)i * 128 + cc));  // read-once
        }
#pragma unroll
        for (int rb = 0; rb < 3; ++rb) {
            int r = rr + rb * 32;
            int swz = (r & 7) << 4;
            *(bf16x8*)(C + r * 512 + ((2 * cc) ^ swz))       = hv[rb];
            *(bf16x8*)(C + r * 512 + ((256 + 2 * cc) ^ swz)) = fv[rb];
        }
    }
    __syncthreads();

    // ---- P2: hb = relu(C @ Wc^T + bc); C := [ h[i] | hb ] ----
    {
        fx4 acc[3][2] = {};
        gemm_block<8>(C, Wp, lane, wm, wc, acc);
        // hrow loads deferred here: issued after gemm, consumed after barrier
        bf16x8 hrow[3];
        if (L == 0) {
#pragma unroll
            for (int rb = 0; rb < 3; ++rb) {
                const fx4* qp = (const fx4*)(h32 + (size_t)ii[rb] * 128 + cc);
                fx4 q0 = qp[0], q1 = qp[1];
#pragma unroll
                for (int j = 0; j < 4; ++j) { hrow[rb][j] = (__bf16)q0[j]; hrow[rb][4 + j] = (__bf16)q1[j]; }
            }
        } else {
#pragma unroll
            for (int rb = 0; rb < 3; ++rb)
                hrow[rb] = *(const bf16x8*)(hsrc + (size_t)ii[rb] * 128 + cc);
        }
        float bb0 = bc[wc * 32 + rl], bb1 = bc[wc * 32 + 16 + rl];
        __syncthreads();     // all reads of C done
#pragma unroll
        for (int m = 0; m < 3; ++m)
#pragma unroll
            for (int c = 0; c < 2; ++c) {
                int col = wc * 32 + c * 16 + rl;
                float bb = c ? bb1 : bb0;
#pragma unroll
                for (int g = 0; g < 4; ++g) {
                    int row = wm * 48 + m * 16 + ks * 4 + g;
                    float v = fmaxf(acc[m][c][g] + bb, 0.0f);
                    *(__bf16*)(C + row * 512 + ((256 + 2 * col) ^ ((row & 7) << 4))) = (__bf16)v;
                }
            }
#pragma unroll
        for (int rb = 0; rb < 3; ++rb) {
            int r = rr + rb * 32;
            *(bf16x8*)(C + r * 512 + ((2 * cc) ^ ((r & 7) << 4))) = hrow[rb];
        }
    }
    __syncthreads();

    // ---- P3: m1 = relu(x @ mW1^T + mb1) -> C first half ----
    {
        fx4 acc[3][2] = {};
        gemm_block<8>(C, Wp + 32768, lane, wm, wc, acc);
        float bb0 = mb1[wc * 32 + rl], bb1 = mb1[wc * 32 + 16 + rl];
        __syncthreads();
#pragma unroll
        for (int m = 0; m < 3; ++m)
#pragma unroll
            for (int c = 0; c < 2; ++c) {
                int col = wc * 32 + c * 16 + rl;
                float bb = c ? bb1 : bb0;
#pragma unroll
                for (int g = 0; g < 4; ++g) {
                    int row = wm * 48 + m * 16 + ks * 4 + g;
                    float v = fmaxf(acc[m][c][g] + bb, 0.0f);
                    *(__bf16*)(C + row * 512 + ((2 * col) ^ ((row & 7) << 4))) = (__bf16)v;
                }
            }
    }
    __syncthreads();

    // ---- P4: out = m1 @ mW2^T + mb2 (K=128), repack via LDS, store ----
    {
        fx4 acc[3][2] = {};
        gemm_block<4>(C, Wp + 65536, lane, wm, wc, acc);
        float bb0 = mb2[wc * 32 + rl], bb1 = mb2[wc * 32 + 16 + rl];
        __syncthreads();
        if (L == 0) {
#pragma unroll
            for (int m = 0; m < 3; ++m)
#pragma unroll
                for (int c = 0; c < 2; ++c) {
                    int col = wc * 32 + c * 16 + rl;
                    float bb = c ? bb1 : bb0;
#pragma unroll
                    for (int g = 0; g < 4; ++g) {
                        int row = wm * 48 + m * 16 + ks * 4 + g;
                        *(__bf16*)(C + row * 256 + 2 * col) = (__bf16)(acc[m][c][g] + bb);
                    }
                }
            __syncthreads();
#pragma unroll
            for (int it = 0; it < 3; ++it) {
                int r = rr + 32 * it;
                int i = r0 + r;
                if (i < NN) {
                    bf16x8 v = *(const bf16x8*)(C + r * 256 + (tid & 15) * 16);
                    __builtin_nontemporal_store(v,
                        (bf16x8*)((char*)hnext + (size_t)i * 256 + (tid & 15) * 16));
                }
            }
        } else {
#pragma unroll
            for (int m = 0; m < 3; ++m)
#pragma unroll
                for (int c = 0; c < 2; ++c) {
                    int col = wc * 32 + c * 16 + rl;
                    float bb = c ? bb1 : bb0;
#pragma unroll
                    for (int g = 0; g < 4; ++g) {
                        int row = wm * 48 + m * 16 + ks * 4 + g;
                        *(float*)(C + row * 512 + 4 * col) = acc[m][c][g] + bb;
                    }
                }
            __syncthreads();
#pragma unroll
            for (int it = 0; it < 6; ++it) {
                int r = (tid >> 5) + 16 * it;
                int i = r0 + r;
                if (i < NN) {
                    fx4 v = *(const fx4*)(C + r * 512 + (tid & 31) * 16);
                    __builtin_nontemporal_store(v,
                        (fx4*)((char*)out32 + (size_t)i * 512 + (tid & 31) * 16));
                }
            }
        }
    }
}

extern "C" void kernel_launch(void* const* d_in, const int* in_sizes, int n_in,
                              void* d_out, int out_size, void* d_ws, size_t ws_size,
                              hipStream_t stream) {
    const float* h    = (const float*)d_in[0];
    const float* feat = (const float*)d_in[1];
    const float* ts   = (const float*)d_in[2];
    const float* lu   = (const float*)d_in[3];
    const float* tw   = (const float*)d_in[4];
    const float* tb   = (const float*)d_in[5];
    const float* W1   = (const float*)d_in[6];
    const float* b1   = (const float*)d_in[7];
    const float* W2   = (const float*)d_in[8];
    const float* b2   = (const float*)d_in[9];
    const float* mW1  = (const float*)d_in[10];
    const float* mb1  = (const float*)d_in[11];
    const float* mW2  = (const float*)d_in[12];
    const float* mb2  = (const float*)d_in[13];
    const int*   src  = (const int*)d_in[14];

    char* ws = (char*)d_ws;
    __bf16* Wp  = (__bf16*)ws;                        // 163840 B
    float*  bcb = (float*)(ws + 163840);              // 512 B
    __bf16* fte = (__bf16*)(ws + 196608);             // 128 MB
    __bf16* h1  = (__bf16*)(ws + 196608 + 128000000); // 128 MB
    float*  out = (float*)d_out;

    prep_w<<<dim3(128), dim3(256), 0, stream>>>(W1, W2, mW1, mW2, b1, b2, Wp, bcb);
    int grid = (NN + TM - 1) / TM;   // 5209
    tgn_layer<0><<<dim3(grid), dim3(512), 0, stream>>>(h, feat, ts, lu, tw, tb,
        nullptr, fte, src, Wp, bcb, mb1, mb2, h1, nullptr);
    tgn_layer<1><<<dim3(grid), dim3(512), 0, stream>>>(nullptr, nullptr, nullptr,
        nullptr, nullptr, nullptr, h1, fte, src, Wp, bcb, mb1, mb2, nullptr, out);
}